// Round 8
// baseline (1763.110 us; speedup 1.0000x reference)
//
#include <hip/hip_runtime.h>
#include <hip/hip_bf16.h>
#include <cstdint>
#include <cstddef>

// out[B,OUT] = (x * alpha) @ W,  W[i,o] = exp(-||col_i - row_o||^2)
// B=8192, IN=4096, OUT=4096.  f32 in/out.
//
// k0 (fused prep): x f32 -> bf16 Xb ; Wt[o][i] = alpha[i]*exp(-d2) bf16 (B^T)
// k1: 256x256 GEMM, BK=32, 64 KiB LDS -> TWO blocks/CU (4 waves/SIMD): the
//     second resident block's waves fill the first's sync bubbles (m114
//     wave-level overlap) -- the r5-r7 rounds showed the 1-block/CU schedule
//     plateaus at ~53% MfmaUtil regardless of intra-block scheduling.
//
// Per K-tile (BK=32): 2 phases, r5-style skeleton {STAGE; [vmcnt]; barrier;
// reads; setprio MFMA}:
//   p0(t): stage B(t+1)->buf^1; vmcnt(2); barrier; read B n0..3 + A m0..3;
//          16 MFMA (mq0 x n0..3)
//   p1(t): stage A(t+1)->buf^1; barrier; read A m4..7; 16 MFMA (mq1)
// Outstanding-load invariant at p0(t) entry: {B(t):2, A(t):2}; after stage 6;
// vmcnt(2) leaves {B(t+1)} => confirms B(t),A(t) BEFORE any tile-t read (RAW).
// WAR: B(t+1) overwrites buf^1.B last read at p0(t-1) -- barrier(p1,t-1)
// intervenes; A(t+1) overwrites buf^1.A last read at p1(t-1) -- barrier(p0,t)
// intervenes.  Trailing vmcnt(0) quiesces strays before exit (LDS re-alloc
// safety for the next block on this CU).
// BK=32 makes every fragment read span the full 64B LDS row -> each wave's
// ds_read_b128 covers a contiguous 1KB region: conflict-free with NO swizzle;
// staging (global_load_lds) and reads are both linear.

#define IN_DIM  4096
#define OUT_DIM 4096
#define BATCH   8192

#define BM 256
#define BN 256
#define BK 32
#define KTILES (IN_DIM / BK)   // 128
#define THREADS 512

#define BUFOFF 16384           // elems per buffer (A 8192 + B 8192) = 32 KiB

#define NCONV  (BATCH * IN_DIM / (256 * 8))   // 16384 convert blocks
#define NWTB   (OUT_DIM * 2)                  // 8192 wt blocks

typedef __bf16 bf16x8 __attribute__((ext_vector_type(8)));
typedef float  f32x4  __attribute__((ext_vector_type(4)));

// ---------------------------------------------------------------------------
// Fused prep: blocks [0,NCONV) convert x; blocks [NCONV, NCONV+NWTB) build Wt.
// ---------------------------------------------------------------------------
__global__ __launch_bounds__(256) void prep_kernel(
    const float* __restrict__ x,
    const float* __restrict__ rows_mean,     // [OUT,2]
    const float* __restrict__ columns_mean,  // [IN,2]
    const float* __restrict__ alpha,         // [IN]
    __bf16* __restrict__ xb,                 // [BATCH][IN]
    __bf16* __restrict__ Wt)                 // [OUT][IN]
{
    const int b = blockIdx.x;
    if (b < NCONV) {
        const size_t i = ((size_t)b * 256 + threadIdx.x) * 8;
        const float4 v0 = *(const float4*)(x + i);
        const float4 v1 = *(const float4*)(x + i + 4);
        bf16x8 o;
        o[0] = (__bf16)v0.x; o[1] = (__bf16)v0.y; o[2] = (__bf16)v0.z; o[3] = (__bf16)v0.w;
        o[4] = (__bf16)v1.x; o[5] = (__bf16)v1.y; o[6] = (__bf16)v1.z; o[7] = (__bf16)v1.w;
        *(bf16x8*)(xb + i) = o;
    } else {
        const int bb = b - NCONV;
        const int o  = bb >> 1;
        const int i0 = ((bb & 1) * 256 + threadIdx.x) * 8;

        const float r0 = rows_mean[2 * o];
        const float r1 = rows_mean[2 * o + 1];

        const float4* cm = (const float4*)(columns_mean + 2 * (size_t)i0);
        float4 c01 = cm[0], c23 = cm[1], c45 = cm[2], c67 = cm[3];
        const float4* ap = (const float4*)(alpha + i0);
        float4 a0 = ap[0], a1 = ap[1];

        float cx[8] = {c01.x, c01.z, c23.x, c23.z, c45.x, c45.z, c67.x, c67.z};
        float cy[8] = {c01.y, c01.w, c23.y, c23.w, c45.y, c45.w, c67.y, c67.w};
        float av[8] = {a0.x, a0.y, a0.z, a0.w, a1.x, a1.y, a1.z, a1.w};

        bf16x8 w;
#pragma unroll
        for (int j = 0; j < 8; ++j) {
            float d0 = cx[j] - r0;
            float d1 = cy[j] - r1;
            w[j] = (__bf16)(__expf(-(d0 * d0 + d1 * d1)) * av[j]);
        }
        *(bf16x8*)(Wt + (size_t)o * IN_DIM + i0) = w;
    }
}

// ---------------------------------------------------------------------------
__global__ __launch_bounds__(THREADS, 4) void gemm_kernel(
    const __bf16* __restrict__ Xb,   // [BATCH, IN] bf16
    const __bf16* __restrict__ Wt,   // [OUT][IN]   bf16 (B^T)
    float* __restrict__ Out)         // [BATCH, OUT]
{
    __shared__ __align__(16) __bf16 lds[2 * BUFOFF];   // 64 KiB -> 2 blocks/CU

    const int tid  = threadIdx.x;
    const int wave = tid >> 6;
    const int lane = tid & 63;
    const int lh   = lane >> 4;          // 0..3 (k-octet)
    const int lr   = lane & 15;          // row within fragment
    const int wm   = wave >> 2;          // 0..1  (M waves)
    const int wn   = wave & 3;           // 0..3  (N waves)

    // ---- XCD-aware block swizzle (512 wg, 512%8==0) ----
    const int swz  = (blockIdx.x & 7) * 64 + (blockIdx.x >> 3);
    const int m0   = (swz >> 4) * BM;
    const int n0   = (swz & 15) * BN;

    // ---- staging addresses: 2 x 16B chunks/thread per operand, all linear ----
    // chunk c = tid + j*512 -> row c>>2, 8-col (c&3)*8
    const __bf16 *pA[2], *pB[2];
    __bf16 *dA[2], *dB[2];
#pragma unroll
    for (int j = 0; j < 2; ++j) {
        const int c = tid + j * 512;
        pA[j] = Xb + (size_t)(m0 + (c >> 2)) * IN_DIM + ((c & 3) << 3);
        pB[j] = Wt + (size_t)(n0 + (c >> 2)) * IN_DIM + ((c & 3) << 3);
        dA[j] = lds + j * 4096 + wave * 512;          // wave-uniform dest
        dB[j] = lds + 8192 + j * 4096 + wave * 512;
    }

    auto STAGE_A = [&](int kt, int boff) {
#pragma unroll
        for (int j = 0; j < 2; ++j)
            __builtin_amdgcn_global_load_lds(
                (const __attribute__((address_space(1))) unsigned int*)(pA[j] + kt * BK),
                (__attribute__((address_space(3))) unsigned int*)(dA[j] + boff), 16, 0, 0);
    };
    auto STAGE_B = [&](int kt, int boff) {
#pragma unroll
        for (int j = 0; j < 2; ++j)
            __builtin_amdgcn_global_load_lds(
                (const __attribute__((address_space(1))) unsigned int*)(pB[j] + kt * BK),
                (__attribute__((address_space(3))) unsigned int*)(dB[j] + boff), 16, 0, 0);
    };

    // ---- fragment read bases (linear; contiguous 1KB per wave-read) ----
    const __bf16* aRd = lds + (wm * 128 + lr) * BK + lh * 8;
    const __bf16* bRd = lds + 8192 + (wn * 64 + lr) * BK + lh * 8;

    auto RD_A = [&](int m, int bo) -> bf16x8 {
        return *(const bf16x8*)(aRd + bo + m * 512);   // m*16 rows * 32
    };
    auto RD_B = [&](int n, int bo) -> bf16x8 {
        return *(const bf16x8*)(bRd + bo + n * 512);
    };

    f32x4 acc[8][4];
#pragma unroll
    for (int m = 0; m < 8; ++m)
#pragma unroll
        for (int n = 0; n < 4; ++n)
            acc[m][n] = f32x4{0.f, 0.f, 0.f, 0.f};

    // ---- prologue: tile 0 -> buf0 (issue order B then A = steady state) ----
    STAGE_B(0, 0);
    STAGE_A(0, 0);

    for (int t = 0; t < KTILES; ++t) {
        const int bo  = (t & 1) * BUFOFF;
        const int sb  = BUFOFF - bo;
        const int kt1 = (t + 1 < KTILES) ? t + 1 : KTILES - 1;  // clamp benign

        // ===== p0: stage B(t+1); confirm tile t; MFMA mq0 (m0..3 x n0..3) =====
        STAGE_B(kt1, sb);
        asm volatile("s_waitcnt vmcnt(2)" ::: "memory");  // confirms B(t), A(t)
        __builtin_amdgcn_s_barrier();
        bf16x8 bf[4], afL[4], afH[4];
        bf[0] = RD_B(0, bo); bf[1] = RD_B(1, bo);
        bf[2] = RD_B(2, bo); bf[3] = RD_B(3, bo);
#pragma unroll
        for (int mf = 0; mf < 4; ++mf)
            afL[mf] = RD_A(mf, bo);
        __builtin_amdgcn_s_setprio(1);
#pragma unroll
        for (int mf = 0; mf < 4; ++mf)
#pragma unroll
            for (int nf = 0; nf < 4; ++nf)
                acc[mf][nf] = __builtin_amdgcn_mfma_f32_16x16x32_bf16(
                    afL[mf], bf[nf], acc[mf][nf], 0, 0, 0);
        __builtin_amdgcn_s_setprio(0);

        // ===== p1: stage A(t+1); MFMA mq1 (m4..7 x n0..3) =====
        STAGE_A(kt1, sb);
        __builtin_amdgcn_s_barrier();
#pragma unroll
        for (int mf = 0; mf < 4; ++mf)
            afH[mf] = RD_A(4 + mf, bo);
        __builtin_amdgcn_s_setprio(1);
#pragma unroll
        for (int mf = 0; mf < 4; ++mf)
#pragma unroll
            for (int nf = 0; nf < 4; ++nf)
                acc[4 + mf][nf] = __builtin_amdgcn_mfma_f32_16x16x32_bf16(
                    afH[mf], bf[nf], acc[4 + mf][nf], 0, 0, 0);
        __builtin_amdgcn_s_setprio(0);
    }

    // quiesce stray prefetches before LDS hand-off to the next block on this CU
    asm volatile("s_waitcnt vmcnt(0)" ::: "memory");

    // ---- epilogue: C/D layout col=lane&15, row=(lane>>4)*4+j ----
    const int crow = m0 + wm * 128 + lh * 4;
    const int ccol = n0 + wn * 64 + lr;
#pragma unroll
    for (int m = 0; m < 8; ++m)
#pragma unroll
        for (int n = 0; n < 4; ++n) {
            float* o = Out + (size_t)(crow + m * 16) * OUT_DIM + (ccol + n * 16);
#pragma unroll
            for (int j = 0; j < 4; ++j)
                o[(size_t)j * OUT_DIM] = acc[m][n][j];
        }
}

// ---------------------------------------------------------------------------
extern "C" void kernel_launch(void* const* d_in, const int* in_sizes, int n_in,
                              void* d_out, int out_size, void* d_ws, size_t ws_size,
                              hipStream_t stream) {
    const float* x  = (const float*)d_in[0];   // [8192, 4096]
    const float* rm = (const float*)d_in[1];   // [4096, 2]
    const float* cm = (const float*)d_in[2];   // [4096, 2]
    const float* al = (const float*)d_in[3];   // [4096]
    float* out = (float*)d_out;                // [8192, 4096]

    __bf16* Wt = (__bf16*)d_ws;                                     // 32 MiB
    __bf16* Xb = (__bf16*)((char*)d_ws + (size_t)32 * 1024 * 1024); // 64 MiB

    prep_kernel<<<NCONV + NWTB, 256, 0, stream>>>(x, rm, cm, al, Xb, Wt);

    dim3 g2((BATCH / BM) * (OUT_DIM / BN));    // 512 = 2 blocks/CU exactly
    gemm_kernel<<<g2, THREADS, 0, stream>>>(Xb, Wt, out);
}

// Round 9
// 315.796 us; speedup vs baseline: 5.5831x; 5.5831x over previous
//
#include <hip/hip_runtime.h>
#include <hip/hip_bf16.h>
#include <cstdint>
#include <cstddef>

// out[B,OUT] = (x * alpha) @ W,  W[i,o] = exp(-||col_i - row_o||^2)
// B=8192, IN=4096, OUT=4096.  f32 in/out.
//
// k0 (fused prep): x f32 -> bf16 Xb ; Wt[o][i] = alpha[i]*exp(-d2) bf16 (B^T)
// k1: 256x128 GEMM, BK=32, 48 KiB LDS, acc 64 VGPR/thread -> TWO blocks/CU
//     (4 waves/SIMD).  r8 failed because 256x256's acc[8][4]=128 VGPR spilled
//     under launch_bounds(512,4) (VGPR cap 128) and the BK=32 row layout had
//     8-way bank conflicts.  This round: wave tile 64x64 (acc[4][4]=64 VGPR,
//     total ~115 regs, no spill) + correct chunk-XOR swizzle for 64B rows.
//
// Per K-tile (BK=32, single phase): {STAGE 3 units(t+1); vmcnt(3); barrier;
// read bf[0..3]+af[0..3]; setprio 16 MFMA; barrier}.
//   Outstanding at entry = 3 (t's, issued at t-1); +3 new; vmcnt(3) confirms
//   t's loads before any read (RAW).  STAGE(t+1)->buf^1 is issued after the
//   end-barrier of t-1, which follows buf^1's last reads at t-1 (WAR).
//   Tail clamp benign (redundant stage to dead buffer); trailing vmcnt(0)
//   quiesces strays before LDS handoff to the next block on this CU.
// Swizzle (row stride 64B = 4 x 16B chunks): chunk c of row r stored at
// c ^ (r&3).  Fragment read lane(lr,lh): bank-group = (lr*4 + (lh^(lr&3)))%8
// -> each of 8 groups gets exactly 8 lanes = minimal 8-cy b128, conflict-free.
// Staging pre-swizzles the per-lane GLOBAL address; LDS dest stays linear
// (global_load_lds wave-uniform-base rule).

#define IN_DIM  4096
#define OUT_DIM 4096
#define BATCH   8192

#define BM 256
#define BN 128
#define BK 32
#define KTILES (IN_DIM / BK)   // 128
#define THREADS 512

#define A_ELEMS 8192           // 256*32
#define BUFOFF  12288          // A 8192 + B 4096 elems = 24 KiB
// total LDS = 2*BUFOFF*2B = 48 KiB -> 2 blocks/CU

#define NCONV  (BATCH * IN_DIM / (256 * 8))   // 16384 convert blocks
#define NWTB   (OUT_DIM * 2)                  // 8192 wt blocks

typedef __bf16 bf16x8 __attribute__((ext_vector_type(8)));
typedef float  f32x4  __attribute__((ext_vector_type(4)));

// ---------------------------------------------------------------------------
// Fused prep: blocks [0,NCONV) convert x; blocks [NCONV, NCONV+NWTB) build Wt.
// ---------------------------------------------------------------------------
__global__ __launch_bounds__(256) void prep_kernel(
    const float* __restrict__ x,
    const float* __restrict__ rows_mean,     // [OUT,2]
    const float* __restrict__ columns_mean,  // [IN,2]
    const float* __restrict__ alpha,         // [IN]
    __bf16* __restrict__ xb,                 // [BATCH][IN]
    __bf16* __restrict__ Wt)                 // [OUT][IN]
{
    const int b = blockIdx.x;
    if (b < NCONV) {
        const size_t i = ((size_t)b * 256 + threadIdx.x) * 8;
        const float4 v0 = *(const float4*)(x + i);
        const float4 v1 = *(const float4*)(x + i + 4);
        bf16x8 o;
        o[0] = (__bf16)v0.x; o[1] = (__bf16)v0.y; o[2] = (__bf16)v0.z; o[3] = (__bf16)v0.w;
        o[4] = (__bf16)v1.x; o[5] = (__bf16)v1.y; o[6] = (__bf16)v1.z; o[7] = (__bf16)v1.w;
        *(bf16x8*)(xb + i) = o;
    } else {
        const int bb = b - NCONV;
        const int o  = bb >> 1;
        const int i0 = ((bb & 1) * 256 + threadIdx.x) * 8;

        const float r0 = rows_mean[2 * o];
        const float r1 = rows_mean[2 * o + 1];

        const float4* cm = (const float4*)(columns_mean + 2 * (size_t)i0);
        float4 c01 = cm[0], c23 = cm[1], c45 = cm[2], c67 = cm[3];
        const float4* ap = (const float4*)(alpha + i0);
        float4 a0 = ap[0], a1 = ap[1];

        float cx[8] = {c01.x, c01.z, c23.x, c23.z, c45.x, c45.z, c67.x, c67.z};
        float cy[8] = {c01.y, c01.w, c23.y, c23.w, c45.y, c45.w, c67.y, c67.w};
        float av[8] = {a0.x, a0.y, a0.z, a0.w, a1.x, a1.y, a1.z, a1.w};

        bf16x8 w;
#pragma unroll
        for (int j = 0; j < 8; ++j) {
            float d0 = cx[j] - r0;
            float d1 = cy[j] - r1;
            w[j] = (__bf16)(__expf(-(d0 * d0 + d1 * d1)) * av[j]);
        }
        *(bf16x8*)(Wt + (size_t)o * IN_DIM + i0) = w;
    }
}

// ---------------------------------------------------------------------------
__global__ __launch_bounds__(THREADS, 4) void gemm_kernel(
    const __bf16* __restrict__ Xb,   // [BATCH, IN] bf16
    const __bf16* __restrict__ Wt,   // [OUT][IN]   bf16 (B^T)
    float* __restrict__ Out)         // [BATCH, OUT]
{
    __shared__ __align__(16) __bf16 lds[2 * BUFOFF];   // 48 KiB

    const int tid  = threadIdx.x;
    const int wave = tid >> 6;
    const int lane = tid & 63;
    const int lh   = lane >> 4;          // 0..3 (k-octet)
    const int lr   = lane & 15;          // row within fragment
    const int wm   = wave >> 1;          // 0..3  (M waves)
    const int wn   = wave & 1;           // 0..1  (N waves)

    // ---- XCD-aware block swizzle (1024 wg, 1024%8==0) ----
    const int swz  = (blockIdx.x & 7) * 128 + (blockIdx.x >> 3);
    const int m0   = (swz >> 5) * BM;    // 32 m-tiles
    const int n0   = (swz & 31) * BN;    // 32 n-tiles

    // ---- staging: A 1024 chunks (2/thread), B 512 chunks (1/thread) ----
    // physical chunk p -> row r=p>>2, phys col cp=p&3 holds logical cl=cp^(r&3)
    const __bf16 *pAg[2], *pBg;
#pragma unroll
    for (int j = 0; j < 2; ++j) {
        const int c  = wave * 64 + lane + j * 512;
        const int r  = c >> 2;
        const int cl = (c & 3) ^ (r & 3);
        pAg[j] = Xb + (size_t)(m0 + r) * IN_DIM + cl * 8;
    }
    {
        const int c  = wave * 64 + lane;
        const int r  = c >> 2;
        const int cl = (c & 3) ^ (r & 3);
        pBg = Wt + (size_t)(n0 + r) * IN_DIM + cl * 8;
    }

    auto STAGE = [&](int kt, int boff) {
        __builtin_amdgcn_global_load_lds(
            (const __attribute__((address_space(1))) unsigned int*)(pAg[0] + kt * BK),
            (__attribute__((address_space(3))) unsigned int*)(lds + boff + wave * 512), 16, 0, 0);
        __builtin_amdgcn_global_load_lds(
            (const __attribute__((address_space(1))) unsigned int*)(pAg[1] + kt * BK),
            (__attribute__((address_space(3))) unsigned int*)(lds + boff + 4096 + wave * 512), 16, 0, 0);
        __builtin_amdgcn_global_load_lds(
            (const __attribute__((address_space(1))) unsigned int*)(pBg + kt * BK),
            (__attribute__((address_space(3))) unsigned int*)(lds + boff + A_ELEMS + wave * 512), 16, 0, 0);
    };

    // ---- fragment read bases (swizzled chunk: phys = lh ^ (lr&3)) ----
    const int cpx = (lh ^ (lr & 3)) * 8;
    const __bf16* aRd = lds + (wm * 64 + lr) * BK + cpx;
    const __bf16* bRd = lds + A_ELEMS + (wn * 64 + lr) * BK + cpx;

    f32x4 acc[4][4];
#pragma unroll
    for (int m = 0; m < 4; ++m)
#pragma unroll
        for (int n = 0; n < 4; ++n)
            acc[m][n] = f32x4{0.f, 0.f, 0.f, 0.f};

    // ---- prologue: tile 0 -> buf0 (3 loads outstanding) ----
    STAGE(0, 0);

    for (int t = 0; t < KTILES; ++t) {
        const int bo  = (t & 1) * BUFOFF;
        const int sb  = BUFOFF - bo;
        const int kt1 = (t + 1 < KTILES) ? t + 1 : KTILES - 1;  // clamp benign

        STAGE(kt1, sb);
        asm volatile("s_waitcnt vmcnt(3)" ::: "memory");  // confirm tile t
        __builtin_amdgcn_s_barrier();

        bf16x8 bf[4], af[4];
        bf[0] = *(const bf16x8*)(bRd + bo + 0 * 512);
        bf[1] = *(const bf16x8*)(bRd + bo + 1 * 512);
        bf[2] = *(const bf16x8*)(bRd + bo + 2 * 512);
        bf[3] = *(const bf16x8*)(bRd + bo + 3 * 512);
#pragma unroll
        for (int m = 0; m < 4; ++m)
            af[m] = *(const bf16x8*)(aRd + bo + m * 512);

        __builtin_amdgcn_s_setprio(1);
#pragma unroll
        for (int m = 0; m < 4; ++m)
#pragma unroll
            for (int n = 0; n < 4; ++n)
                acc[m][n] = __builtin_amdgcn_mfma_f32_16x16x32_bf16(
                    af[m], bf[n], acc[m][n], 0, 0, 0);
        __builtin_amdgcn_s_setprio(0);
        __builtin_amdgcn_s_barrier();
    }

    // quiesce stray prefetches before LDS hand-off to the next block on this CU
    asm volatile("s_waitcnt vmcnt(0)" ::: "memory");

    // ---- epilogue: C/D layout col=lane&15, row=(lane>>4)*4+j ----
    const int crow = m0 + wm * 64 + lh * 4;
    const int ccol = n0 + wn * 64 + lr;
#pragma unroll
    for (int m = 0; m < 4; ++m)
#pragma unroll
        for (int n = 0; n < 4; ++n) {
            float* o = Out + (size_t)(crow + m * 16) * OUT_DIM + (ccol + n * 16);
#pragma unroll
            for (int j = 0; j < 4; ++j)
                o[(size_t)j * OUT_DIM] = acc[m][n][j];
        }
}

// ---------------------------------------------------------------------------
extern "C" void kernel_launch(void* const* d_in, const int* in_sizes, int n_in,
                              void* d_out, int out_size, void* d_ws, size_t ws_size,
                              hipStream_t stream) {
    const float* x  = (const float*)d_in[0];   // [8192, 4096]
    const float* rm = (const float*)d_in[1];   // [4096, 2]
    const float* cm = (const float*)d_in[2];   // [4096, 2]
    const float* al = (const float*)d_in[3];   // [4096]
    float* out = (float*)d_out;                // [8192, 4096]

    __bf16* Wt = (__bf16*)d_ws;                                     // 32 MiB
    __bf16* Xb = (__bf16*)((char*)d_ws + (size_t)32 * 1024 * 1024); // 64 MiB

    prep_kernel<<<NCONV + NWTB, 256, 0, stream>>>(x, rm, cm, al, Xb, Wt);

    dim3 g2((BATCH / BM) * (OUT_DIM / BN));    // 1024 blocks, 2 resident/CU
    gemm_kernel<<<g2, THREADS, 0, stream>>>(Xb, Wt, out);
}

// Round 10
// 274.663 us; speedup vs baseline: 6.4192x; 1.1498x over previous
//
#include <hip/hip_runtime.h>
#include <hip/hip_bf16.h>
#include <cstdint>
#include <cstddef>

// out[B,OUT] = (x * alpha) @ W,  W[i,o] = exp(-||col_i - row_o||^2)
// B=8192, IN=4096, OUT=4096.  f32 in/out.
//
// k0 (fused prep): x f32 -> bf16 Xb ; Wt[o][i] = alpha[i]*exp(-d2) bf16 (B^T)
// k1: 256x256 GEMM, BK=64, 8 waves (2M x 4N), 4 quadrant-phases/K-tile,
//     m201-faithful skeleton + ZERO-STALL counted vmcnt plan.
//
// Phase skeleton:  [reads for THIS phase: p0=12, p1=4, p2=8, p3=0]
//                  [stage 1 unit (2 gload_lds)]
//                  [vmcnt(6) at p0, p1, p3 -- none at p2]
//                  s_barrier ; lgkmcnt(0)+sched_barrier ;
//                  setprio(1) 16 MFMA setprio(0) ; s_barrier
// Reads issue at phase START (drain in the barrier shadow, consumed same
// phase after lgkmcnt(0)); MFMA cluster issues clean.
// Stage cadence: p0(t):B0(t+1), p1:B1(t+1), p2:A1(t+1), p3:A0(t+2).
// Wait chain (each confirms loads staged >=3 phases earlier => landed, ~0 cy):
//   p3(t-1) vmcnt(6): confirms A0(t)[4ph], B0(t)[3ph]  -> read at p0(t)
//   p0(t)   vmcnt(6): confirms B1(t)[3ph]              -> read at p1(t)
//   p1(t)   vmcnt(6): confirms A1(t)[3ph]              -> read at p2(t)
//   steady-state outstanding cycles 6->8->6 (floor 6, never drains).
//   [This fixes r7's regression: its lone vmcnt(2)@p3 confirmed a 1-phase-old
//    unit = full HBM-latency stall every tile for all 8 waves.]
// WAR: every stage targets a slot whose last ds_read was >=4 phases (>=4
// barriers) earlier.  Tail: kt clamps benign (dead-region rewrites).
// LDS layout (conflict-free, measured 0 in r5-r7): unit = [128 rows][64 k],
// 16B chunk kc of row rho stored at kc ^ (rho&7); staging pre-swizzles the
// per-lane GLOBAL address (LDS dest linear per gload_lds rule).

#define IN_DIM  4096
#define OUT_DIM 4096
#define BATCH   8192

#define BM 256
#define BN 256
#define BK 64
#define KTILES (IN_DIM / BK)   // 64
#define THREADS 512

#define UNIT   8192            // elems per stage unit (128 rows * 64)
#define OPOFF  16384           // A (2 units) -> B offset
#define BUFOFF 32768           // elems per buffer (A + B)

#define NCONV  (BATCH * IN_DIM / (256 * 8))   // 16384 convert blocks
#define NWTB   (OUT_DIM * 2)                  // 8192 wt blocks

typedef __bf16 bf16x8 __attribute__((ext_vector_type(8)));
typedef float  f32x4  __attribute__((ext_vector_type(4)));

// ---------------------------------------------------------------------------
// Fused prep: blocks [0,NCONV) convert x; blocks [NCONV, NCONV+NWTB) build Wt.
// ---------------------------------------------------------------------------
__global__ __launch_bounds__(256) void prep_kernel(
    const float* __restrict__ x,
    const float* __restrict__ rows_mean,     // [OUT,2]
    const float* __restrict__ columns_mean,  // [IN,2]
    const float* __restrict__ alpha,         // [IN]
    __bf16* __restrict__ xb,                 // [BATCH][IN]
    __bf16* __restrict__ Wt)                 // [OUT][IN]
{
    const int b = blockIdx.x;
    if (b < NCONV) {
        const size_t i = ((size_t)b * 256 + threadIdx.x) * 8;
        const float4 v0 = *(const float4*)(x + i);
        const float4 v1 = *(const float4*)(x + i + 4);
        bf16x8 o;
        o[0] = (__bf16)v0.x; o[1] = (__bf16)v0.y; o[2] = (__bf16)v0.z; o[3] = (__bf16)v0.w;
        o[4] = (__bf16)v1.x; o[5] = (__bf16)v1.y; o[6] = (__bf16)v1.z; o[7] = (__bf16)v1.w;
        *(bf16x8*)(xb + i) = o;
    } else {
        const int bb = b - NCONV;
        const int o  = bb >> 1;
        const int i0 = ((bb & 1) * 256 + threadIdx.x) * 8;

        const float r0 = rows_mean[2 * o];
        const float r1 = rows_mean[2 * o + 1];

        const float4* cm = (const float4*)(columns_mean + 2 * (size_t)i0);
        float4 c01 = cm[0], c23 = cm[1], c45 = cm[2], c67 = cm[3];
        const float4* ap = (const float4*)(alpha + i0);
        float4 a0 = ap[0], a1 = ap[1];

        float cx[8] = {c01.x, c01.z, c23.x, c23.z, c45.x, c45.z, c67.x, c67.z};
        float cy[8] = {c01.y, c01.w, c23.y, c23.w, c45.y, c45.w, c67.y, c67.w};
        float av[8] = {a0.x, a0.y, a0.z, a0.w, a1.x, a1.y, a1.z, a1.w};

        bf16x8 w;
#pragma unroll
        for (int j = 0; j < 8; ++j) {
            float d0 = cx[j] - r0;
            float d1 = cy[j] - r1;
            w[j] = (__bf16)(__expf(-(d0 * d0 + d1 * d1)) * av[j]);
        }
        *(bf16x8*)(Wt + (size_t)o * IN_DIM + i0) = w;
    }
}

// ---------------------------------------------------------------------------
__global__ __launch_bounds__(THREADS, 2) void gemm_kernel(
    const __bf16* __restrict__ Xb,   // [BATCH, IN] bf16
    const __bf16* __restrict__ Wt,   // [OUT][IN]   bf16 (B^T)
    float* __restrict__ Out)         // [BATCH, OUT]
{
    __shared__ __align__(16) __bf16 lds[2 * BUFOFF];   // 128 KiB

    const int tid  = threadIdx.x;
    const int wave = tid >> 6;
    const int lane = tid & 63;
    const int lh   = lane >> 4;          // 0..3
    const int lr   = lane & 15;
    const int wm   = wave >> 2;          // 0..1  (M waves)
    const int wn   = wave & 3;           // 0..3  (N waves)

    // ---- XCD-aware block swizzle (512 wg, 512%8==0) ----
    const int swz  = (blockIdx.x & 7) * 64 + (blockIdx.x >> 3);
    const int m0   = (swz >> 4) * BM;
    const int n0   = (swz & 15) * BN;

    // ---- staging precompute (2 loads/thread per unit) ----
    const __bf16 *pA[2], *pB[2];
    __bf16 *lA[2], *lB[2];
#pragma unroll
    for (int j = 0; j < 2; ++j) {
        const int c  = wave * 64 + lane + j * 512;
        const int rp = c >> 3;
        const int kg = (c & 7) ^ (rp & 7);
        const int rA = ((rp >> 6) & 1) * 128 + (rp & 63);
        const int rB = (rp >> 5) * 64 + (rp & 31);
        pA[j] = Xb + (size_t)(m0 + rA) * IN_DIM + kg * 8;
        pB[j] = Wt + (size_t)(n0 + rB) * IN_DIM + kg * 8;
        lA[j] = lds + j * 4096 + wave * 512;          // wave-uniform dest
        lB[j] = lds + OPOFF + j * 4096 + wave * 512;
    }

    auto STAGE_A = [&](int kt, int h, int b) {
#pragma unroll
        for (int j = 0; j < 2; ++j)
            __builtin_amdgcn_global_load_lds(
                (const __attribute__((address_space(1))) unsigned int*)
                    (pA[j] + (size_t)h * 64 * IN_DIM + kt * BK),
                (__attribute__((address_space(3))) unsigned int*)
                    (lA[j] + b * BUFOFF + h * UNIT), 16, 0, 0);
    };
    auto STAGE_B = [&](int kt, int h, int b) {
#pragma unroll
        for (int j = 0; j < 2; ++j)
            __builtin_amdgcn_global_load_lds(
                (const __attribute__((address_space(1))) unsigned int*)
                    (pB[j] + (size_t)h * 32 * IN_DIM + kt * BK),
                (__attribute__((address_space(3))) unsigned int*)
                    (lB[j] + b * BUFOFF + h * UNIT), 16, 0, 0);
    };

    // ---- fragment read bases (swizzled chunks; rho&7 == lr&7) ----
    const int l7  = lr & 7;
    const int sc0 = lh ^ l7;          // kk=0 chunk
    const int sc1 = (4 + lh) ^ l7;    // kk=1 chunk
    const __bf16* aB = lds + (wm * 64 + lr) * 64;
    const __bf16* bB = lds + OPOFF + (wn * 32 + lr) * 64;

    auto RD_A = [&](int m, int kk, int bo) -> bf16x8 {
        return *(const bf16x8*)(aB + bo + (m >> 2) * UNIT + (m & 3) * 1024
                                + (kk ? sc1 : sc0) * 8);
    };
    auto RD_B = [&](int n, int kk, int bo) -> bf16x8 {
        return *(const bf16x8*)(bB + bo + (n >> 1) * UNIT + (n & 1) * 1024
                                + (kk ? sc1 : sc0) * 8);
    };

    f32x4 acc[8][4];
#pragma unroll
    for (int m = 0; m < 8; ++m)
#pragma unroll
        for (int n = 0; n < 4; ++n)
            acc[m][n] = f32x4{0.f, 0.f, 0.f, 0.f};

    // ---- prologue: tile 0 (4 units) -> buf0, A0(1) -> buf1 ----
    STAGE_A(0, 0, 0); STAGE_B(0, 0, 0); STAGE_B(0, 1, 0); STAGE_A(0, 1, 0);
    STAGE_A(1, 0, 1);
    asm volatile("s_waitcnt vmcnt(6)" ::: "memory");   // confirm A0(0), B0(0)
    __builtin_amdgcn_s_barrier();

    for (int t = 0; t < KTILES; ++t) {
        const int bo  = (t & 1) * BUFOFF;
        const int sb1 = (t & 1) ^ 1;     // buffer of tile t+1
        const int sb2 = (t & 1);         // buffer of tile t+2
        const int kt1 = (t + 1 < KTILES) ? t + 1 : KTILES - 1;  // clamp benign
        const int kt2 = (t + 2 < KTILES) ? t + 2 : KTILES - 1;

        bf16x8 afL[4][2], afH[4][2], bL[4], bH[4];

        // ===== p0: (mq0,nq0): reads bL+afL; stage B0(t+1); vmcnt(6) =====
        bL[0] = RD_B(0, 0, bo); bL[1] = RD_B(0, 1, bo);
        bL[2] = RD_B(1, 0, bo); bL[3] = RD_B(1, 1, bo);
#pragma unroll
        for (int mf = 0; mf < 4; ++mf) {
            afL[mf][0] = RD_A(mf, 0, bo);
            afL[mf][1] = RD_A(mf, 1, bo);
        }
        STAGE_B(kt1, 0, sb1);
        asm volatile("s_waitcnt vmcnt(6)" ::: "memory");   // confirm B1(t)
        __builtin_amdgcn_s_barrier();
        asm volatile("s_waitcnt lgkmcnt(0)" ::: "memory");
        __builtin_amdgcn_sched_barrier(0);
        __builtin_amdgcn_s_setprio(1);
#pragma unroll
        for (int kk = 0; kk < 2; ++kk)
#pragma unroll
            for (int mf = 0; mf < 4; ++mf)
#pragma unroll
                for (int nf = 0; nf < 2; ++nf)
                    acc[mf][nf] = __builtin_amdgcn_mfma_f32_16x16x32_bf16(
                        afL[mf][kk], bL[nf * 2 + kk], acc[mf][nf], 0, 0, 0);
        __builtin_amdgcn_s_setprio(0);
        __builtin_amdgcn_s_barrier();

        // ===== p1: (mq0,nq1): reads bH; stage B1(t+1); vmcnt(6) =====
        bH[0] = RD_B(2, 0, bo); bH[1] = RD_B(2, 1, bo);
        bH[2] = RD_B(3, 0, bo); bH[3] = RD_B(3, 1, bo);
        STAGE_B(kt1, 1, sb1);
        asm volatile("s_waitcnt vmcnt(6)" ::: "memory");   // confirm A1(t)
        __builtin_amdgcn_s_barrier();
        asm volatile("s_waitcnt lgkmcnt(0)" ::: "memory");
        __builtin_amdgcn_sched_barrier(0);
        __builtin_amdgcn_s_setprio(1);
#pragma unroll
        for (int kk = 0; kk < 2; ++kk)
#pragma unroll
            for (int mf = 0; mf < 4; ++mf)
#pragma unroll
                for (int nf = 0; nf < 2; ++nf)
                    acc[mf][2 + nf] = __builtin_amdgcn_mfma_f32_16x16x32_bf16(
                        afL[mf][kk], bH[nf * 2 + kk], acc[mf][2 + nf], 0, 0, 0);
        __builtin_amdgcn_s_setprio(0);
        __builtin_amdgcn_s_barrier();

        // ===== p2: (mq1,nq0): reads afH; stage A1(t+1); no wait =====
#pragma unroll
        for (int mf = 0; mf < 4; ++mf) {
            afH[mf][0] = RD_A(4 + mf, 0, bo);
            afH[mf][1] = RD_A(4 + mf, 1, bo);
        }
        STAGE_A(kt1, 1, sb1);
        __builtin_amdgcn_s_barrier();
        asm volatile("s_waitcnt lgkmcnt(0)" ::: "memory");
        __builtin_amdgcn_sched_barrier(0);
        __builtin_amdgcn_s_setprio(1);
#pragma unroll
        for (int kk = 0; kk < 2; ++kk)
#pragma unroll
            for (int mf = 0; mf < 4; ++mf)
#pragma unroll
                for (int nf = 0; nf < 2; ++nf)
                    acc[4 + mf][nf] = __builtin_amdgcn_mfma_f32_16x16x32_bf16(
                        afH[mf][kk], bL[nf * 2 + kk], acc[4 + mf][nf], 0, 0, 0);
        __builtin_amdgcn_s_setprio(0);
        __builtin_amdgcn_s_barrier();

        // ===== p3: (mq1,nq1): no reads; stage A0(t+2); vmcnt(6) =====
        STAGE_A(kt2, 0, sb2);
        asm volatile("s_waitcnt vmcnt(6)" ::: "memory");   // confirm A0,B0(t+1)
        __builtin_amdgcn_s_barrier();
        __builtin_amdgcn_s_setprio(1);
#pragma unroll
        for (int kk = 0; kk < 2; ++kk)
#pragma unroll
            for (int mf = 0; mf < 4; ++mf)
#pragma unroll
                for (int nf = 0; nf < 2; ++nf)
                    acc[4 + mf][2 + nf] = __builtin_amdgcn_mfma_f32_16x16x32_bf16(
                        afH[mf][kk], bH[nf * 2 + kk], acc[4 + mf][2 + nf], 0, 0, 0);
        __builtin_amdgcn_s_setprio(0);
        __builtin_amdgcn_s_barrier();
    }

    // ---- epilogue: C/D layout col=lane&15, row=(lane>>4)*4+j ----
    const int crow = m0 + wm * 128 + lh * 4;
    const int ccol = n0 + wn * 64 + lr;
#pragma unroll
    for (int m = 0; m < 8; ++m)
#pragma unroll
        for (int n = 0; n < 4; ++n) {
            float* o = Out + (size_t)(crow + m * 16) * OUT_DIM + (ccol + n * 16);
#pragma unroll
            for (int j = 0; j < 4; ++j)
                o[(size_t)j * OUT_DIM] = acc[m][n][j];
        }
}

// ---------------------------------------------------------------------------
extern "C" void kernel_launch(void* const* d_in, const int* in_sizes, int n_in,
                              void* d_out, int out_size, void* d_ws, size_t ws_size,
                              hipStream_t stream) {
    const float* x  = (const float*)d_in[0];   // [8192, 4096]
    const float* rm = (const float*)d_in[1];   // [4096, 2]
    const float* cm = (const float*)d_in[2];   // [4096, 2]
    const float* al = (const float*)d_in[3];   // [4096]
    float* out = (float*)d_out;                // [8192, 4096]

    __bf16* Wt = (__bf16*)d_ws;                                     // 32 MiB
    __bf16* Xb = (__bf16*)((char*)d_ws + (size_t)32 * 1024 * 1024); // 64 MiB

    prep_kernel<<<NCONV + NWTB, 256, 0, stream>>>(x, rm, cm, al, Xb, Wt);

    dim3 g2((BATCH / BM) * (OUT_DIM / BN));    // 512
    gemm_kernel<<<g2, THREADS, 0, stream>>>(Xb, Wt, out);
}